// Round 1
// baseline (597.471 us; speedup 1.0000x reference)
//
#include <hip/hip_runtime.h>
#include <math.h>

// ExpertGating: g = x @ gate_w^T + gate_b  (16384x4096 @ 4096x64)
//               top-8 (sorted desc, tie -> lowest index), softmax over 8.
// d_out (float32, single-dtype readback): [0,131072) weights, [131072,262144) indices-as-float.
//
// fp64 accumulation: index output threshold (2% of 63) demands near-exact rank
// order vs the fp64 numpy reference; fp32 accumulation (~1e-5 logit error)
// would produce O(10) rank swaps across 16384 rows. fp64 error ~1e-13 -> safe.

#define NUM_TOKENS 16384
#define HID 4096
#define NE 64
#define TOPK 8
#define BT 32          // tokens per block
#define BK 64          // K-chunk
#define WSTRIDE 66     // padded LDS stride (doubles): 66*8=528 B, 16B-aligned, breaks pow2 banks

__global__ __launch_bounds__(256, 2)
void gating_kernel(const float* __restrict__ x,
                   const float* __restrict__ gw,
                   const float* __restrict__ gb,
                   float* __restrict__ out) {
    // 64x66 + 32x66 doubles = 50.7 KB static LDS (<64 KB); 2 blocks/CU -> 101 KB/CU (<160 KB)
    __shared__ double ws_d[NE][WSTRIDE];
    __shared__ double xs_d[BT][WSTRIDE];

    const int tid  = threadIdx.x;
    const int tok0 = blockIdx.x * BT;

    // thread -> 2 tokens x 4 experts; experts strided by 16 so ds_read_b128 of
    // w rows lands 2 addresses/bank-group (free per m136).
    const int e0 = tid & 15;         // experts e0, e0+16, e0+32, e0+48
    const int t2 = (tid >> 4) * 2;   // tokens t2, t2+1

    double acc[2][4];
#pragma unroll
    for (int i = 0; i < 2; i++)
#pragma unroll
        for (int j = 0; j < 4; j++) acc[i][j] = 0.0;

    for (int k0 = 0; k0 < HID; k0 += BK) {
        // ---- stage x tile (32x64 f32) -> LDS fp64 (convert once per block, not per use)
#pragma unroll
        for (int i = 0; i < 2; i++) {
            int idx = i * 256 + tid;
            int tt  = idx >> 4;
            int cc  = (idx & 15) << 2;
            float4 v = *(const float4*)(x + (size_t)(tok0 + tt) * HID + k0 + cc);
            xs_d[tt][cc + 0] = (double)v.x;
            xs_d[tt][cc + 1] = (double)v.y;
            xs_d[tt][cc + 2] = (double)v.z;
            xs_d[tt][cc + 3] = (double)v.w;
        }
        // ---- stage w tile (64x64 f32, all experts) -> LDS fp64
#pragma unroll
        for (int i = 0; i < 4; i++) {
            int idx = i * 256 + tid;
            int ee  = idx >> 4;
            int cc  = (idx & 15) << 2;
            float4 v = *(const float4*)(gw + (size_t)ee * HID + k0 + cc);
            ws_d[ee][cc + 0] = (double)v.x;
            ws_d[ee][cc + 1] = (double)v.y;
            ws_d[ee][cc + 2] = (double)v.z;
            ws_d[ee][cc + 3] = (double)v.w;
        }
        __syncthreads();

        const double* xr0 = &xs_d[t2 + 0][0];
        const double* xr1 = &xs_d[t2 + 1][0];
        const double* w0  = &ws_d[e0 +  0][0];
        const double* w1  = &ws_d[e0 + 16][0];
        const double* w2  = &ws_d[e0 + 32][0];
        const double* w3  = &ws_d[e0 + 48][0];

#pragma unroll 8
        for (int kk = 0; kk < BK; kk++) {
            double xa = xr0[kk], xb = xr1[kk];
            double a0 = w0[kk], a1 = w1[kk], a2 = w2[kk], a3 = w3[kk];
            acc[0][0] = fma(xa, a0, acc[0][0]);
            acc[0][1] = fma(xa, a1, acc[0][1]);
            acc[0][2] = fma(xa, a2, acc[0][2]);
            acc[0][3] = fma(xa, a3, acc[0][3]);
            acc[1][0] = fma(xb, a0, acc[1][0]);
            acc[1][1] = fma(xb, a1, acc[1][1]);
            acc[1][2] = fma(xb, a2, acc[1][2]);
            acc[1][3] = fma(xb, a3, acc[1][3]);
        }
        __syncthreads();  // also protects ws_d before the lg alias below
    }

    // ---- logits to LDS (alias over dead ws_d; 32*65=2080 doubles <= 64*66=4224)
    double* lg = &ws_d[0][0];
#pragma unroll
    for (int i = 0; i < 2; i++) {
        int t = t2 + i;
#pragma unroll
        for (int j = 0; j < 4; j++) {
            int e = e0 + 16 * j;
            lg[t * 65 + e] = acc[i][j] + (double)gb[e];
        }
    }
    __syncthreads();

    // ---- top-8 + softmax: 8 lanes of each wave handle 8 tokens (32 total)
    const int wv = tid >> 6, ln = tid & 63;
    if (ln < 8) {
        int t = wv * 8 + ln;
        const double* row = lg + t * 65;
        unsigned long long sel = 0ull;
        double vals[TOPK];
        int idxs[TOPK];
#pragma unroll
        for (int k = 0; k < TOPK; k++) {
            double bv = -1e300;
            int bi = 0;
            for (int e = 0; e < NE; e++) {
                bool valid = !((sel >> e) & 1ull);
                double v = row[e];
                bool take = valid && (v > bv);   // strict > : lowest index wins ties (jax top_k)
                bv = take ? v : bv;
                bi = take ? e : bi;
            }
            sel |= 1ull << bi;
            vals[k] = bv;
            idxs[k] = bi;
        }
        double m = vals[0];
        float ex[TOPK];
        float s = 0.f;
#pragma unroll
        for (int k = 0; k < TOPK; k++) {
            ex[k] = expf((float)(vals[k] - m));
            s += ex[k];
        }
        float inv = 1.0f / s;
        float* ow = out;
        float* oi = out + NUM_TOKENS * TOPK;
        int gt = tok0 + t;
#pragma unroll
        for (int k = 0; k < TOPK; k++) {
            ow[gt * TOPK + k] = ex[k] * inv;
            oi[gt * TOPK + k] = (float)idxs[k];
        }
    }
}

extern "C" void kernel_launch(void* const* d_in, const int* in_sizes, int n_in,
                              void* d_out, int out_size, void* d_ws, size_t ws_size,
                              hipStream_t stream) {
    const float* x  = (const float*)d_in[0];
    const float* gw = (const float*)d_in[1];
    const float* gb = (const float*)d_in[2];
    float* out = (float*)d_out;

    dim3 grid(NUM_TOKENS / BT);  // 512 blocks
    dim3 block(256);
    gating_kernel<<<grid, block, 0, stream>>>(x, gw, gb, out);
}